// Round 6
// baseline (278.351 us; speedup 1.0000x reference)
//
#include <hip/hip_runtime.h>

#define BB 16
#define HH 512
#define WW 512
#define HWP (HH*WW)
#define NMAP (BB*HWP)

// ---------------------------------------------------------------------------
// One guided-filter stage, fully fused, R=4 row-batched:
//   box1(s,q) [v-running colsum + LDS h-exchange] -> pointwise A,b
//   -> box1(A,b) [LDS h-exchange -> h-sums; VERTICAL sum via per-thread
//      statically-indexed register shift queue — no LDS ring, no 3rd sync]
//   -> emit.
// 2 __syncthreads per 4 output rows (compiler drains vmcnt(0) at every
// barrier, so barrier count is the stall — amortize it).
// Rows r >= HH or < 0 contribute ZERO: they are neither added (re guard)
// nor subtracted (rl guard — rl CAN reach HH on the last chunk since
// NIT*R overshoots; unguarded this read 2KB past x and crashed, round 5).
// STAGE 1: input x -> s,q on the fly; emits mA1,mb1 and updated s',q'.
// STAGE 2: input s,q; emits mA2,mb2 and updated s'',q''.
// STAGE 3: input s,q; emit folds mA1..mb2 + x + w1 into the final output.
// ---------------------------------------------------------------------------
template <int PAD, int CH, int STAGE>
__global__ __launch_bounds__(256) void stagek(
    const float* __restrict__ p0, const float* __restrict__ p1,
    const float* __restrict__ p2, const float* __restrict__ p3,
    const float* __restrict__ p4, const float* __restrict__ p5,
    const float* __restrict__ px, const float* __restrict__ w1,
    float* __restrict__ o0, float* __restrict__ o1,
    float* __restrict__ o2, float* __restrict__ o3, float eps)
{
    constexpr int R = 4;
    constexpr int Q = 2 * PAD + 1;                  // v-window depth
    constexpr int XW = 256 + 4 * PAD;               // pass-1 colsum space
    constexpr int AW = 256 + 2 * PAD;               // A-column space
    constexpr int NCH = HH / CH;
    constexpr int NIT = (CH + 2 * PAD + R - 1) / R;

    __shared__ float ex1[R][2][XW];
    __shared__ float ex2[R][2][AW];
    __shared__ float wsh[27];

    const int bx = blockIdx.x;
    const int chunk = bx % NCH;
    const int strip = (bx / NCH) & 1;
    const int b = bx / (NCH * 2);
    const int t = threadIdx.x;
    const int w0 = strip * 256;
    const int w = w0 + t;
    const int h0 = chunk * CH;
    const size_t mb_ = (size_t)b * HWP;
    const size_t xb_ = (size_t)b * 3 * HWP;

    if (STAGE == 3 && t < 27) wsh[t] = w1[t];

    // pass-1 halo: 2P cols/side ; pass-2 (A) halo: P cols/side
    const bool lh1 = (t < 2 * PAD), rh1 = (t >= 256 - 2 * PAD);
    const int  h1col = lh1 ? (w0 - 2 * PAD + t) : (w + 2 * PAD);
    const int  h1idx = lh1 ? t : (t + 4 * PAD);
    const bool h1 = lh1 || rh1;
    const bool h1v = h1 && ((unsigned)h1col < (unsigned)WW);
    const bool lh2 = (t < PAD), rh2 = (t >= 256 - PAD);
    const int  a2col = lh2 ? (w0 - PAD + t) : (w + PAD);
    const int  a2idx = lh2 ? t : (t + 2 * PAD);
    const bool h2 = lh2 || rh2;
    const bool h2v = h2 && ((unsigned)a2col < (unsigned)WW);

    auto ldsq = [&](int r, int c, float& sv, float& qv) {
        if constexpr (STAGE == 1) {
            size_t ii = xb_ + (size_t)r * WW + c;
            float a0 = px[ii], a1 = px[ii + HWP], a2 = px[ii + 2 * HWP];
            sv = a0 + a1 + a2;
            qv = a0 * a0 + a1 * a1 + a2 * a2;
        } else {
            size_t ii = mb_ + (size_t)r * WW + c;
            sv = p0[ii]; qv = p1[ii];
        }
    };

    // prime pass-1 colsum for virtual A-row (h0-P-1): rows [h0-2P-1, h0-1]
    float cs0 = 0.f, cs1 = 0.f, hcs0 = 0.f, hcs1 = 0.f;
    for (int rr = h0 - 2 * PAD - 1; rr < h0; ++rr) {
        if (rr >= 0) {
            float sv, qv;
            ldsq(rr, w, sv, qv); cs0 += sv; cs1 += qv;
            if (h1v) { ldsq(rr, h1col, sv, qv); hcs0 += sv; hcs1 += qv; }
        }
    }

    // pass-2 register shift queue (rows rbase-Q .. rbase-1), all-static indexing
    float qA[Q], qB[Q];
#pragma unroll
    for (int i = 0; i < Q; ++i) { qA[i] = 0.f; qB[i] = 0.f; }
    float csA = 0.f, csB = 0.f;

    for (int k = 0; k < NIT; ++k) {
        const int rbase = h0 - PAD + k * R;

        // ---- batched enter/leave loads (issued together for MLP) ----
        float en0[R], en1[R], lv0[R], lv1[R];
        float he0[R], he1[R], hl0[R], hl1[R];
#pragma unroll
        for (int j = 0; j < R; ++j) {
            const int re = rbase + j + PAD;
            const int rl = rbase + j - PAD - 1;
            en0[j] = en1[j] = lv0[j] = lv1[j] = 0.f;
            he0[j] = he1[j] = hl0[j] = hl1[j] = 0.f;
            if ((unsigned)re < (unsigned)HH) {
                ldsq(re, w, en0[j], en1[j]);
                if (h1v) ldsq(re, h1col, he0[j], he1[j]);
            }
            if ((unsigned)rl < (unsigned)HH) {       // rl can hit HH on last chunk!
                ldsq(rl, w, lv0[j], lv1[j]);
                if (h1v) ldsq(rl, h1col, hl0[j], hl1[j]);
            }
        }
#pragma unroll
        for (int j = 0; j < R; ++j) {
            cs0 += en0[j] - lv0[j];
            cs1 += en1[j] - lv1[j];
            ex1[j][0][t + 2 * PAD] = cs0;
            ex1[j][1][t + 2 * PAD] = cs1;
            if (h1) {
                hcs0 += he0[j] - hl0[j];             // stays 0 when !h1v
                hcs1 += he1[j] - hl1[j];
                ex1[j][0][h1idx] = hcs0;
                ex1[j][1][h1idx] = hcs1;
            }
        }
        __syncthreads();

        // ---- pass-1 h-sums -> pointwise A,b -> ex2 (own + P-halo cols) ----
#pragma unroll
        for (int j = 0; j < R; ++j) {
            const int r = rbase + j;
            const bool rin = (unsigned)r < (unsigned)HH;
            float Am = 0.f, Bm = 0.f, Ah = 0.f, Bh = 0.f;
            if (rin) {
                const int hlo = r - PAD < 0 ? 0 : r - PAD;
                const int hhi = r + PAD > HH - 1 ? HH - 1 : r + PAD;
                const float rowc = (float)(hhi - hlo + 1);
                float ss = 0.f, qq = 0.f;
#pragma unroll
                for (int d = 0; d <= 2 * PAD; ++d) {
                    ss += ex1[j][0][t + PAD + d];
                    qq += ex1[j][1][t + PAD + d];
                }
                const int wlo = w - PAD < 0 ? 0 : w - PAD;
                const int whi = w + PAD > WW - 1 ? WW - 1 : w + PAD;
                float Nc = 3.f * rowc * (float)(whi - wlo + 1);
                float mean = ss / Nc;
                float var = qq / Nc - mean * mean;
                Am = var / (var + eps);
                Bm = mean * (1.f - Am);
                if (h2v) {
                    float s2 = 0.f, q2 = 0.f;
#pragma unroll
                    for (int d = 0; d <= 2 * PAD; ++d) {
                        s2 += ex1[j][0][a2idx + d];
                        q2 += ex1[j][1][a2idx + d];
                    }
                    const int wlo2 = a2col - PAD < 0 ? 0 : a2col - PAD;
                    const int whi2 = a2col + PAD > WW - 1 ? WW - 1 : a2col + PAD;
                    float Nc2 = 3.f * rowc * (float)(whi2 - wlo2 + 1);
                    float mean2 = s2 / Nc2;
                    float var2 = q2 / Nc2 - mean2 * mean2;
                    Ah = var2 / (var2 + eps);
                    Bh = mean2 * (1.f - Ah);
                }
            }
            ex2[j][0][t + PAD] = Am;
            ex2[j][1][t + PAD] = Bm;
            if (h2) { ex2[j][0][a2idx] = Ah; ex2[j][1][a2idx] = Bh; }
        }
        __syncthreads();

        // ---- pass-2 h-sums; vertical box via register queue (syncless) ----
        float hA[R], hB[R];
#pragma unroll
        for (int j = 0; j < R; ++j) {
            float a = 0.f, bb = 0.f;
#pragma unroll
            for (int d = 0; d <= 2 * PAD; ++d) {
                a += ex2[j][0][t + d];
                bb += ex2[j][1][t + d];
            }
            hA[j] = a; hB[j] = bb;
        }
        float oA[R], oB[R];
        {
            float accA = csA, accB = csB;
#pragma unroll
            for (int j = 0; j < R; ++j) {
                const float subA = (j < Q) ? qA[j] : hA[j - Q];
                const float subB = (j < Q) ? qB[j] : hB[j - Q];
                accA += hA[j] - subA;
                accB += hB[j] - subB;
                oA[j] = accA; oB[j] = accB;
            }
            csA = accA; csB = accB;
        }
#pragma unroll
        for (int i = 0; i < Q; ++i) {                // shift by R, static idx
            const int src = i + R;
            qA[i] = (src < Q) ? qA[src] : hA[src - Q];
            qB[i] = (src < Q) ? qB[src] : hB[src - Q];
        }

        // ---- emit (thread-local, syncless) ----
#pragma unroll
        for (int j = 0; j < R; ++j) {
            const int h = rbase + j - PAD;
            if (h >= h0 && h < h0 + CH) {
                const size_t oi = mb_ + (size_t)h * WW + w;
                if constexpr (STAGE == 3) {
                    float a1 = 3.f * p2[oi], b1 = 3.f * p3[oi];
                    float a2v = 3.f * p4[oi], b2v = 3.f * p5[oi];
                    float a3 = 3.f * oA[j], b3 = 3.f * oB[j];
                    float P1 = a1,        Q1 = b1;
                    float P2 = a2v * P1,  Q2 = a2v * Q1 + b2v;
                    float P3 = a3 * P2,   Q3 = a3 * Q2 + b3;
                    float al[3] = {1.f - P1, P1 - P2, P2 - P3};
                    float be[3] = {-Q1,      Q1 - Q2, Q2 - Q3};
                    const size_t xi = xb_ + (size_t)h * WW + w;
                    float x0 = px[xi], x1 = px[xi + HWP], x2 = px[xi + 2 * HWP];
#pragma unroll
                    for (int o = 0; o < 3; ++o) {
                        float acc = 0.f;
#pragma unroll
                        for (int g = 0; g < 3; ++g) {
                            float wa = wsh[o * 9 + g * 3 + 0];
                            float wb = wsh[o * 9 + g * 3 + 1];
                            float wc = wsh[o * 9 + g * 3 + 2];
                            acc += al[g] * (wa * x0 + wb * x1 + wc * x2)
                                 + be[g] * (wa + wb + wc);
                        }
                        o0[xi + (size_t)o * HWP] = acc;
                    }
                } else {
                    float mAr = oA[j], mbr = oB[j];
                    o0[oi] = mAr; o1[oi] = mbr;
                    float sv, qv;
                    ldsq(h, w, sv, qv);              // L2/L3 hit (recent row)
                    float mA = 3.f * mAr, mbv = 3.f * mbr;
                    o2[oi] = mA * sv + 3.f * mbv;
                    o3[oi] = mA * mA * qv + 2.f * mA * mbv * sv + 3.f * mbv * mbv;
                }
            }
        }
    }
}

extern "C" void kernel_launch(void* const* d_in, const int* in_sizes, int n_in,
                              void* d_out, int out_size, void* d_ws, size_t ws_size,
                              hipStream_t stream) {
    (void)in_sizes; (void)n_in; (void)out_size; (void)ws_size;
    const float* x  = (const float*)d_in[0];
    const float* w1 = (const float*)d_in[1];
    float* out = (float*)d_out;
    float* ws = (float*)d_ws;

    // 8 maps of B*H*W floats = 134 MB workspace
    float* sA  = ws + 0ull * NMAP;
    float* qA  = ws + 1ull * NMAP;
    float* sB  = ws + 2ull * NMAP;
    float* qB  = ws + 3ull * NMAP;
    float* mA1 = ws + 4ull * NMAP;
    float* mb1 = ws + 5ull * NMAP;
    float* mA2 = ws + 6ull * NMAP;
    float* mb2 = ws + 7ull * NMAP;

    dim3 bl(256);
    dim3 g16(BB * 2 * (HH / 16));                    // 1024 blocks, 4/CU

    // stage 1: k=3 (PAD=1), eps=0.16 — x -> mA1,mb1 + s',q'
    stagek<1, 16, 1><<<g16, bl, 0, stream>>>(
        nullptr, nullptr, nullptr, nullptr, nullptr, nullptr, x, w1,
        mA1, mb1, sA, qA, 0.16f);

    // stage 2: k=7 (PAD=3), eps=0.04 — s',q' -> mA2,mb2 + s'',q''
    stagek<3, 16, 2><<<g16, bl, 0, stream>>>(
        sA, qA, nullptr, nullptr, nullptr, nullptr, x, w1,
        mA2, mb2, sB, qB, 0.04f);

    // stage 3: k=15 (PAD=7), eps=0.01 — s'',q'' + mA1..mb2 + x -> out
    stagek<7, 16, 3><<<g16, bl, 0, stream>>>(
        sB, qB, mA1, mb1, mA2, mb2, x, w1,
        out, nullptr, nullptr, nullptr, 0.01f);
}